// Round 9
// baseline (209.982 us; speedup 1.0000x reference)
//
#include <hip/hip_runtime.h>
#include <hip/hip_bf16.h>
#include <stdint.h>

typedef __hip_bfloat16 bf16_t;
typedef __attribute__((ext_vector_type(8))) __bf16 bf16x8;
typedef __attribute__((ext_vector_type(4))) float f32x4;
typedef __attribute__((ext_vector_type(8))) unsigned short ushort8;
typedef __attribute__((ext_vector_type(2))) unsigned long long u64x2;

#define BM 256
#define BN 256
#define BK 64
#define THREADS 512
#define OPBYTES 32768   // one operand per buf: 256 rows x 128 B
#define BUFBYTES 65536  // A + B
#define LDS_TOTAL 131072

// ---------------- fused quantize: q = rint(v*100)/100, cast to bf16 ----------------
__global__ __launch_bounds__(256) void quant2_bf16_kernel(
    const float* __restrict__ x, const float* __restrict__ w,
    bf16_t* __restrict__ q, long axn8, long totn8) {
  long idx = (long)blockIdx.x * blockDim.x + threadIdx.x;
  long stride = (long)gridDim.x * blockDim.x;
  for (long i = idx; i < totn8; i += stride) {
    const float* src = (i < axn8) ? (x + i * 8) : (w + (i - axn8) * 8);
    const float4* p = reinterpret_cast<const float4*>(src);
    float4 v0 = p[0];
    float4 v1 = p[1];
    float vv[8] = {v0.x, v0.y, v0.z, v0.w, v1.x, v1.y, v1.z, v1.w};
    ushort8 r;
#pragma unroll
    for (int j = 0; j < 8; ++j) {
      float qq = rintf(vv[j] * 100.0f) / 100.0f;  // half-to-even, matches jnp.round
      __hip_bfloat16 h = __float2bfloat16(qq);
      r[j] = __builtin_bit_cast(unsigned short, h);
    }
    u64x2 u = __builtin_bit_cast(u64x2, r);
    unsigned long long* dst = reinterpret_cast<unsigned long long*>(q + i * 8);
    __hip_atomic_store(dst + 0, u[0], __ATOMIC_RELAXED, __HIP_MEMORY_SCOPE_AGENT);
    __hip_atomic_store(dst + 1, u[1], __ATOMIC_RELAXED, __HIP_MEMORY_SCOPE_AGENT);
  }
}

// ---------------- fallback ----------------
__global__ void naive_kernel(const float* __restrict__ x, const float* __restrict__ W,
                             const float* __restrict__ b, float* __restrict__ out,
                             int M, int N, int K) {
  int o = blockIdx.x * blockDim.x + threadIdx.x;
  int m = blockIdx.y;
  if (o >= N || m >= M) return;
  float s = 0.f;
  for (int k = 0; k < K; ++k) {
    float qx = rintf(x[(size_t)m * K + k] * 100.f) / 100.f;
    float qw = rintf(W[(size_t)o * K + k] * 100.f) / 100.f;
    s += qx * qw;
  }
  float v = s + b[o];
  __hip_atomic_store(out + (size_t)m * N + o, v, __ATOMIC_RELAXED,
                     __HIP_MEMORY_SCOPE_AGENT);
}

__device__ __forceinline__ void gload_lds16(const bf16_t* g, const char* l) {
  __builtin_amdgcn_global_load_lds(
      (const __attribute__((address_space(1))) unsigned int*)g,
      (__attribute__((address_space(3))) unsigned int*)l, 16, 0, 0);
}

#define BARRIER()                               \
  do {                                          \
    asm volatile("" ::: "memory");              \
    __builtin_amdgcn_s_barrier();               \
    asm volatile("" ::: "memory");              \
  } while (0)
#define VM4() asm volatile("s_waitcnt vmcnt(4)" ::: "memory")
#define VM0() asm volatile("s_waitcnt vmcnt(0)" ::: "memory")

// ---------------- bf16 GEMM, B^T input: C[m][n] = sum_k A[m][k]*B[n][k] + bias[n]
// 4-SUPER-PHASE schedule (round 9): rounds 6-8 showed 8 narrow phases keep all
// 8 waves lockstep -> LDS pipe and MFMA pipe ping-pong (9190 cyc/iter = MFMA
// 4966 + reads ~4100, serial). Wider windows (32 MFMA + 8-16 reads + 1 stage,
// ONE barrier) give the compiler counted-lgkm interleave room and let the
// 2 waves/SIMD skew so one reads while the other MFMAs.
//
// Iter p (tiles t0=2p,t1=2p+1 resident; t2=t0+2, t3=t0+3):
//  P1: read b0.B-lo,B-hi,A-lo (16); stage b1.A(t1) [4 loads];
//      MMA(0,0,blo)+MMA(0,1,bhi); barrier
//  P2: read b0.A-hi (8); stage b0.B(t2); MMA(1,1,bhi)+MMA(1,0,blo);
//      VM4; barrier
//  P3: read b1.B-lo,B-hi,A-lo (16); stage b0.A(t2); MMA(0,0)+MMA(0,1); barrier
//  P4: read b1.A-hi (8); stage b1.B(t3); MMA(1,1)+MMA(1,0); VM4; barrier
//
// WAR (>=1 barrier between last read of region and its overwrite):
//   b1.A last read P4(prev) -> staged P1; b0.B last read P1 -> P2;
//   b0.A last read P2 -> P3; b1.B last read P3 -> P4.  Reads drain before
//   their phase barrier (each read feeds an MFMA in the same phase).
// vmcnt ledger (per-thread loads, oldest-first; stage region = 4 loads):
//   enter P1: 4 in flight [b1.B(t1)]. P1 +4 -> 8. P2 +4 -> 12; VM4 retires 8
//   [b1.B(t1),b1.A(t1)] (needed by P3) keeps 4 [b0.B(t2)]. P3 +4 -> 8.
//   P4 +4 -> 12; VM4 retires 8 [b0(t2)] (needed next P1) keeps 4 [b1.B(t3)].
//   Prologue: 12 issued, VM4 -> 4 [b1.B(t1)]. LAST iter PEELED: P1 stages
//   b1.A(nt-1) only; P2 does VM0 (drains all 8); P3/P4 no stage/VM.
// LDS swizzle: 128B rows, stored slot = slot ^ (row&7) (bank-balanced; 0
// conflicts measured r2-r8). global_load_lds dest linear (base+lane*16);
// swizzle applied on the global SOURCE (rule #21).
__global__ __launch_bounds__(THREADS, 2) void gemm_bt_bf16(
    const bf16_t* __restrict__ A,   // [M][K]
    const bf16_t* __restrict__ B,   // [N][K]
    const float* __restrict__ bias, // [N]
    float* __restrict__ C,          // [M][N]
    int M, int N, int K) {
  extern __shared__ char lds[];

  const int tid = threadIdx.x;
  const int lane = tid & 63;
  const int wave = tid >> 6;  // 0..7
  const int wm = wave >> 2;   // 0..1 -> output rows wm*128..+128
  const int wn = wave & 3;    // 0..3 -> output cols wn*64..+64
  const int lr = lane & 15;
  const int lg = lane >> 4;

  // XCD-aware bijective swizzle (nwg % 8 == 0 guaranteed by tiled_ok)
  int nbn = N / BN;
  int nwg = gridDim.x;
  int bid = blockIdx.x;
  int swz = bid;
  if ((nwg & 7) == 0) {
    int cpx = nwg >> 3;
    swz = (bid & 7) * cpx + (bid >> 3);
  }
  const int brow = (swz / nbn) * BM;
  const int bcol = (swz % nbn) * BN;

  // ds_read byte offsets within an operand region (kk=0; kk=1 is ^64)
  int aoffs[8], boffs[4];
#pragma unroll
  for (int m = 0; m < 8; ++m) {
    int r = wm * 128 + m * 16 + lr;
    aoffs[m] = r * 128 + (((lg) ^ (r & 7)) << 4);
  }
#pragma unroll
  for (int n = 0; n < 4; ++n) {
    int r = wn * 64 + n * 16 + lr;
    boffs[n] = r * 128 + (((lg) ^ (r & 7)) << 4);
  }

  f32x4 acc[8][4];
#pragma unroll
  for (int m = 0; m < 8; ++m)
#pragma unroll
    for (int n = 0; n < 4; ++n) acc[m][n] = (f32x4){0.f, 0.f, 0.f, 0.f};

  const int nt = K / BK;

  auto STAGE_A = [&](int h, int kt, int q) {
#pragma unroll
    for (int i = 0; i < 2; ++i) {
      int row = h * 128 + i * 64 + (tid >> 3);
      int L = q * BUFBYTES + row * 128 + ((tid & 7) << 4);
      int slot = (tid & 7) ^ (row & 7);
      gload_lds16(A + (size_t)(brow + row) * K + (size_t)kt * 64 + slot * 8,
                  lds + L);
    }
  };
  auto STAGE_B = [&](int h, int kt, int q) {
#pragma unroll
    for (int i = 0; i < 2; ++i) {
      int row = h * 128 + i * 64 + (tid >> 3);
      int L = q * BUFBYTES + OPBYTES + row * 128 + ((tid & 7) << 4);
      int slot = (tid & 7) ^ (row & 7);
      gload_lds16(B + (size_t)(bcol + row) * K + (size_t)kt * 64 + slot * 8,
                  lds + L);
    }
  };

  bf16x8 aq[8], blo[4], bhi[4];  // A quadrant [mm][kk]; B quadrants [nn][kk]
  auto READ_A = [&](int q, int mh) {
#pragma unroll
    for (int mm = 0; mm < 4; ++mm) {
      int off = q * BUFBYTES + aoffs[mh * 4 + mm];
      aq[mm * 2 + 0] = *reinterpret_cast<const bf16x8*>(lds + off);
      aq[mm * 2 + 1] = *reinterpret_cast<const bf16x8*>(lds + (off ^ 64));
    }
  };
  auto READ_B = [&](int q, int nh, bf16x8* dst) {
#pragma unroll
    for (int nn = 0; nn < 2; ++nn) {
      int off = q * BUFBYTES + OPBYTES + boffs[nh * 2 + nn];
      dst[nn * 2 + 0] = *reinterpret_cast<const bf16x8*>(lds + off);
      dst[nn * 2 + 1] = *reinterpret_cast<const bf16x8*>(lds + (off ^ 64));
    }
  };
  auto MMA = [&](int mh, int nh, const bf16x8* bb) {
    __builtin_amdgcn_s_setprio(1);
#pragma unroll
    for (int mm = 0; mm < 4; ++mm)
#pragma unroll
      for (int nn = 0; nn < 2; ++nn)
#pragma unroll
        for (int kk = 0; kk < 2; ++kk)
          acc[mh * 4 + mm][nh * 2 + nn] = __builtin_amdgcn_mfma_f32_16x16x32_bf16(
              aq[mm * 2 + kk], bb[nn * 2 + kk], acc[mh * 4 + mm][nh * 2 + nn],
              0, 0, 0);
    __builtin_amdgcn_s_setprio(0);
  };

  // Prologue: b0 <- tile0 (full), b1 <- tile1 B region. 12 loads; VM4 retires
  // b0's 8, keeps b1.B's 4 in flight (steady-state P1 entry condition).
  STAGE_B(0, 0, 0); STAGE_B(1, 0, 0);
  STAGE_A(0, 0, 0); STAGE_A(1, 0, 0);
  STAGE_B(0, 1, 1); STAGE_B(1, 1, 1);
  VM4();
  BARRIER();

  const int np = nt >> 1;
  for (int p = 0; p < np - 1; ++p) {
    const int t1 = 2 * p + 1, t2 = 2 * p + 2, t3 = 2 * p + 3;
    // P1: buf0 (m-lo row): both B halves + A-lo; stage b1.A(t1)
    READ_B(0, 0, blo); READ_B(0, 1, bhi); READ_A(0, 0);
    STAGE_A(0, t1, 1); STAGE_A(1, t1, 1);
    MMA(0, 0, blo); MMA(0, 1, bhi);
    BARRIER();
    // P2: buf0 A-hi; stage b0.B(t2); retire b1(t1) for P3
    READ_A(0, 1);
    STAGE_B(0, t2, 0); STAGE_B(1, t2, 0);
    MMA(1, 1, bhi); MMA(1, 0, blo);
    VM4();
    BARRIER();
    // P3: buf1 (m-lo): both B halves + A-lo; stage b0.A(t2)
    READ_B(1, 0, blo); READ_B(1, 1, bhi); READ_A(1, 0);
    STAGE_A(0, t2, 0); STAGE_A(1, t2, 0);
    MMA(0, 0, blo); MMA(0, 1, bhi);
    BARRIER();
    // P4: buf1 A-hi; stage b1.B(t3); retire b0(t2) for next P1
    READ_A(1, 1);
    STAGE_B(0, t3, 1); STAGE_B(1, t3, 1);
    MMA(1, 1, bhi); MMA(1, 0, blo);
    VM4();
    BARRIER();
  }

  // Peeled final iteration (t0=nt-2, t1=nt-1): P1 stages b1.A(t1) (still real
  // data); P2 drains everything (VM0); P3/P4 no stages.
  {
    const int t1 = nt - 1;
    READ_B(0, 0, blo); READ_B(0, 1, bhi); READ_A(0, 0);
    STAGE_A(0, t1, 1); STAGE_A(1, t1, 1);
    MMA(0, 0, blo); MMA(0, 1, bhi);
    BARRIER();
    READ_A(0, 1);
    MMA(1, 1, bhi); MMA(1, 0, blo);
    VM0();
    BARRIER();
    READ_B(1, 0, blo); READ_B(1, 1, bhi); READ_A(1, 0);
    MMA(0, 0, blo); MMA(0, 1, bhi);
    BARRIER();
    READ_A(1, 1);
    MMA(1, 1, bhi); MMA(1, 0, blo);
  }

  // Epilogue: C/D layout col=lane&15, row=(lane>>4)*4+reg  [m89/m91]
  // Agent-scope stores (replay-safe visibility past per-XCD L2).
  const int cn = lane & 15;
  const int r4 = (lane >> 4) << 2;
#pragma unroll
  for (int n = 0; n < 4; ++n) {
    const int gcol = bcol + wn * 64 + n * 16 + cn;
    const float bv = bias[gcol];
#pragma unroll
    for (int m = 0; m < 8; ++m) {
      const int grow = brow + wm * 128 + m * 16 + r4;
      float* outp = C + (size_t)grow * N + gcol;
#pragma unroll
      for (int j = 0; j < 4; ++j) {
        float v = acc[m][n][j] + bv;
        __hip_atomic_store(outp + (size_t)j * N, v, __ATOMIC_RELAXED,
                           __HIP_MEMORY_SCOPE_AGENT);
      }
    }
  }
}

extern "C" void kernel_launch(void* const* d_in, const int* in_sizes, int n_in,
                              void* d_out, int out_size, void* d_ws, size_t ws_size,
                              hipStream_t stream) {
  const float* x = (const float*)d_in[0];
  const float* W = (const float*)d_in[1];
  const float* b = (const float*)d_in[2];
  float* out = (float*)d_out;

  const int N = in_sizes[2];       // D_OUT
  const int K = in_sizes[1] / N;   // D_IN
  const int M = in_sizes[0] / K;   // B rows

  const size_t needA = (size_t)M * K * sizeof(bf16_t);
  const size_t needB = (size_t)N * K * sizeof(bf16_t);
  const bool tiled_ok = (M % BM == 0) && (N % BN == 0) && (K % (2 * BK) == 0) &&
                        (K / BK >= 2) && (ws_size >= needA + needB);
  if (!tiled_ok) {
    dim3 g((unsigned)((N + 255) / 256), (unsigned)M);
    naive_kernel<<<g, 256, 0, stream>>>(x, W, b, out, M, N, K);
    return;
  }

  bf16_t* qA = (bf16_t*)d_ws;
  bf16_t* qB = qA + (size_t)M * K;
  const long axn8 = (long)M * K / 8;
  const long totn8 = axn8 + (long)N * K / 8;
  quant2_bf16_kernel<<<2048, 256, 0, stream>>>(x, W, qA, axn8, totn8);

  (void)hipFuncSetAttribute((const void*)gemm_bt_bf16,
                            hipFuncAttributeMaxDynamicSharedMemorySize, LDS_TOTAL);

  const int nwg = (M / BM) * (N / BN);
  gemm_bt_bf16<<<nwg, THREADS, LDS_TOTAL, stream>>>(qA, qB, b, out, M, N, K);
}

// Round 10
// 185.765 us; speedup vs baseline: 1.1304x; 1.1304x over previous
//
#include <hip/hip_runtime.h>
#include <hip/hip_bf16.h>
#include <stdint.h>

typedef __hip_bfloat16 bf16_t;
typedef __attribute__((ext_vector_type(8))) __bf16 bf16x8;
typedef __attribute__((ext_vector_type(4))) float f32x4;
typedef __attribute__((ext_vector_type(8))) unsigned short ushort8;
typedef __attribute__((ext_vector_type(2))) unsigned long long u64x2;

#define BM 128
#define BN 256
#define BKT 32
#define THREADS 256
#define ABYTES 8192     // A: 128 rows x 64 B
#define BUFBYTES 24576  // A (8 KiB) + B (16 KiB)
#define LDS_TOTAL 73728 // 3 buffers -> 2 blocks/CU (144 KiB of 160)

// ---------------- fused quantize: q = rint(v*100)/100, cast to bf16 ----------------
__global__ __launch_bounds__(256) void quant2_bf16_kernel(
    const float* __restrict__ x, const float* __restrict__ w,
    bf16_t* __restrict__ q, long axn8, long totn8) {
  long idx = (long)blockIdx.x * blockDim.x + threadIdx.x;
  long stride = (long)gridDim.x * blockDim.x;
  for (long i = idx; i < totn8; i += stride) {
    const float* src = (i < axn8) ? (x + i * 8) : (w + (i - axn8) * 8);
    const float4* p = reinterpret_cast<const float4*>(src);
    float4 v0 = p[0];
    float4 v1 = p[1];
    float vv[8] = {v0.x, v0.y, v0.z, v0.w, v1.x, v1.y, v1.z, v1.w};
    ushort8 r;
#pragma unroll
    for (int j = 0; j < 8; ++j) {
      float qq = rintf(vv[j] * 100.0f) / 100.0f;  // half-to-even, matches jnp.round
      __hip_bfloat16 h = __float2bfloat16(qq);
      r[j] = __builtin_bit_cast(unsigned short, h);
    }
    u64x2 u = __builtin_bit_cast(u64x2, r);
    unsigned long long* dst = reinterpret_cast<unsigned long long*>(q + i * 8);
    __hip_atomic_store(dst + 0, u[0], __ATOMIC_RELAXED, __HIP_MEMORY_SCOPE_AGENT);
    __hip_atomic_store(dst + 1, u[1], __ATOMIC_RELAXED, __HIP_MEMORY_SCOPE_AGENT);
  }
}

// ---------------- fallback ----------------
__global__ void naive_kernel(const float* __restrict__ x, const float* __restrict__ W,
                             const float* __restrict__ b, float* __restrict__ out,
                             int M, int N, int K) {
  int o = blockIdx.x * blockDim.x + threadIdx.x;
  int m = blockIdx.y;
  if (o >= N || m >= M) return;
  float s = 0.f;
  for (int k = 0; k < K; ++k) {
    float qx = rintf(x[(size_t)m * K + k] * 100.f) / 100.f;
    float qw = rintf(W[(size_t)o * K + k] * 100.f) / 100.f;
    s += qx * qw;
  }
  float v = s + b[o];
  __hip_atomic_store(out + (size_t)m * N + o, v, __ATOMIC_RELAXED,
                     __HIP_MEMORY_SCOPE_AGENT);
}

__device__ __forceinline__ void gload_lds16(const bf16_t* g, const char* l) {
  __builtin_amdgcn_global_load_lds(
      (const __attribute__((address_space(1))) unsigned int*)g,
      (__attribute__((address_space(3))) unsigned int*)l, 16, 0, 0);
}

#define BARRIER()                               \
  do {                                          \
    asm volatile("" ::: "memory");              \
    __builtin_amdgcn_s_barrier();               \
    asm volatile("" ::: "memory");              \
  } while (0)
#define VM6() asm volatile("s_waitcnt vmcnt(6)" ::: "memory")
#define VM0() asm volatile("s_waitcnt vmcnt(0)" ::: "memory")

// ---------------- bf16 GEMM, B^T input: C[m][n] = sum_k A[m][k]*B[n][k] + bias[n]
// ROUND 10: 2-blocks-per-CU overlap. Rounds 3-9 all landed at 46-48% MfmaUtil:
// per-iter cycles = MFMA floor + LDS-pipe time EXACTLY (9190 = 4966 + ~4200)
// because block-wide barriers keep all waves in the same phase -> the CU-shared
// LDS pipe and the matrix pipe ping-pong. Fix: two INDEPENDENT 4-wave blocks
// per CU (128x256 tile, 72 KiB LDS each) whose phases interleave freely
// (m97/m114 mechanism). Pipeline is round 3's proven loop:
//   prologue: STAGE(t0,b0), STAGE(t1,b1)          [6 loads each]
//   iter t:   VM6 (keep tile t+1's 6 in flight) -> barrier ->
//             STAGE(t+2, buf[(t+2)%3]) -> COMPUTE(buf[t%3])
//   last iter peeled: VM0 -> barrier -> COMPUTE.
// Ledger: entering iter t, outstanding = tiles t (6) + t+1 (6); VM6 retires
// exactly tile t (every wave's, since ALL waves VM6 before the barrier).
// WAR: buf[(t+2)%3] was last read in COMPUTE(t-1), which every wave finished
// before reaching this iteration's barrier. RAW: VM6+barrier precede reads.
// Swizzle: 64 B rows, stored slot = slot ^ ((row>>1)&3) - round 2's geometry,
// measured SQ_LDS_BANK_CONFLICT = 0. global_load_lds dest linear; swizzle on
// the global SOURCE address (rule #21).
__global__ __launch_bounds__(THREADS, 2) void gemm_bt_bf16(
    const bf16_t* __restrict__ A,   // [M][K]
    const bf16_t* __restrict__ B,   // [N][K]
    const float* __restrict__ bias, // [N]
    float* __restrict__ C,          // [M][N]
    int M, int N, int K) {
  extern __shared__ char lds[];

  const int tid = threadIdx.x;
  const int lane = tid & 63;
  const int wave = tid >> 6;  // 0..3
  const int wm = wave >> 1;   // 0..1 -> output rows wm*64..+64
  const int wn = wave & 1;    // 0..1 -> output cols wn*128..+128
  const int lr = lane & 15;
  const int lg = lane >> 4;

  // XCD-aware bijective swizzle (nwg % 8 == 0 guaranteed by tiled_ok)
  int nbn = N / BN;
  int nwg = gridDim.x;
  int bid = blockIdx.x;
  int swz = bid;
  if ((nwg & 7) == 0) {
    int cpx = nwg >> 3;
    swz = (bid & 7) * cpx + (bid >> 3);
  }
  const int brow = (swz / nbn) * BM;
  const int bcol = (swz % nbn) * BN;

  // ds_read byte offsets (loop-invariant; swizzled to match staged layout)
  int aoffs[4], boffs[8];
#pragma unroll
  for (int m = 0; m < 4; ++m) {
    int r = wm * 64 + m * 16 + lr;
    aoffs[m] = r * 64 + (((lg) ^ ((r >> 1) & 3)) << 4);
  }
#pragma unroll
  for (int n = 0; n < 8; ++n) {
    int r = wn * 128 + n * 16 + lr;
    boffs[n] = ABYTES + r * 64 + (((lg) ^ ((r >> 1) & 3)) << 4);
  }

  f32x4 acc[4][8];
#pragma unroll
  for (int m = 0; m < 4; ++m)
#pragma unroll
    for (int n = 0; n < 8; ++n) acc[m][n] = (f32x4){0.f, 0.f, 0.f, 0.f};

  const int nt = K / BKT;

  // Stage one K-tile: A = 2 loads, B = 4 loads per thread (16 B each).
  // Linear LDS dest (base + tid*16 per 4096-B chunk); inverse swizzle on the
  // global source k-slot.
  auto STAGE = [&](int kt, int q) {
#pragma unroll
    for (int i = 0; i < 2; ++i) {
      int row = i * 64 + (tid >> 2);
      int L = q * BUFBYTES + i * 4096 + tid * 16;
      int slot = (tid & 3) ^ ((row >> 1) & 3);
      gload_lds16(A + (size_t)(brow + row) * K + (size_t)kt * BKT + slot * 8,
                  lds + L);
    }
#pragma unroll
    for (int i = 0; i < 4; ++i) {
      int row = i * 64 + (tid >> 2);
      int L = q * BUFBYTES + ABYTES + i * 4096 + tid * 16;
      int slot = (tid & 3) ^ ((row >> 1) & 3);
      gload_lds16(B + (size_t)(bcol + row) * K + (size_t)kt * BKT + slot * 8,
                  lds + L);
    }
  };

  auto COMPUTE = [&](int q) {
    bf16x8 aq[4], bq[8];
#pragma unroll
    for (int m = 0; m < 4; ++m)
      aq[m] = *reinterpret_cast<const bf16x8*>(lds + q * BUFBYTES + aoffs[m]);
#pragma unroll
    for (int n = 0; n < 8; ++n)
      bq[n] = *reinterpret_cast<const bf16x8*>(lds + q * BUFBYTES + boffs[n]);
    __builtin_amdgcn_s_setprio(1);
#pragma unroll
    for (int m = 0; m < 4; ++m)
#pragma unroll
      for (int n = 0; n < 8; ++n)
        acc[m][n] = __builtin_amdgcn_mfma_f32_16x16x32_bf16(aq[m], bq[n],
                                                            acc[m][n], 0, 0, 0);
    __builtin_amdgcn_s_setprio(0);
  };

  // Prologue: 2 tiles in flight (12 loads).
  STAGE(0, 0);
  STAGE(1, 1);

  int q = 0, q2 = 2;
  for (int t = 0; t < nt - 1; ++t) {
    VM6();      // tile t's 6 loads landed (per wave); tile t+1's stay in flight
    BARRIER();  // -> ALL waves' tile-t loads landed; all done reading buf q2
    if (t + 2 < nt) STAGE(t + 2, q2);
    COMPUTE(q);
    q = (q == 2) ? 0 : q + 1;
    q2 = (q2 == 2) ? 0 : q2 + 1;
  }
  VM0();
  BARRIER();
  COMPUTE(q);

  // Epilogue: C/D layout col=lane&15, row=(lane>>4)*4+reg  [m89/m91]
  // Agent-scope stores (replay-safe visibility past per-XCD L2).
  const int cn = lane & 15;
  const int r4 = (lane >> 4) << 2;
#pragma unroll
  for (int n = 0; n < 8; ++n) {
    const int gcol = bcol + wn * 128 + n * 16 + cn;
    const float bv = bias[gcol];
#pragma unroll
    for (int m = 0; m < 4; ++m) {
      const int grow = brow + wm * 64 + m * 16 + r4;
      float* outp = C + (size_t)grow * N + gcol;
#pragma unroll
      for (int j = 0; j < 4; ++j) {
        float v = acc[m][n][j] + bv;
        __hip_atomic_store(outp + (size_t)j * N, v, __ATOMIC_RELAXED,
                           __HIP_MEMORY_SCOPE_AGENT);
      }
    }
  }
}

extern "C" void kernel_launch(void* const* d_in, const int* in_sizes, int n_in,
                              void* d_out, int out_size, void* d_ws, size_t ws_size,
                              hipStream_t stream) {
  const float* x = (const float*)d_in[0];
  const float* W = (const float*)d_in[1];
  const float* b = (const float*)d_in[2];
  float* out = (float*)d_out;

  const int N = in_sizes[2];       // D_OUT
  const int K = in_sizes[1] / N;   // D_IN
  const int M = in_sizes[0] / K;   // B rows

  const size_t needA = (size_t)M * K * sizeof(bf16_t);
  const size_t needB = (size_t)N * K * sizeof(bf16_t);
  const bool tiled_ok = (M % BM == 0) && (N % BN == 0) && (K % BKT == 0) &&
                        (K / BKT >= 2) && (ws_size >= needA + needB);
  if (!tiled_ok) {
    dim3 g((unsigned)((N + 255) / 256), (unsigned)M);
    naive_kernel<<<g, 256, 0, stream>>>(x, W, b, out, M, N, K);
    return;
  }

  bf16_t* qA = (bf16_t*)d_ws;
  bf16_t* qB = qA + (size_t)M * K;
  const long axn8 = (long)M * K / 8;
  const long totn8 = axn8 + (long)N * K / 8;
  quant2_bf16_kernel<<<2048, 256, 0, stream>>>(x, W, qA, axn8, totn8);

  (void)hipFuncSetAttribute((const void*)gemm_bt_bf16,
                            hipFuncAttributeMaxDynamicSharedMemorySize, LDS_TOTAL);

  const int nwg = (M / BM) * (N / BN);
  gemm_bt_bf16<<<nwg, THREADS, LDS_TOTAL, stream>>>(qA, qB, b, out, M, N, K);
}

// Round 11
// 160.069 us; speedup vs baseline: 1.3118x; 1.1605x over previous
//
#include <hip/hip_runtime.h>
#include <hip/hip_bf16.h>
#include <stdint.h>

typedef __hip_bfloat16 bf16_t;
typedef __attribute__((ext_vector_type(8))) __bf16 bf16x8;
typedef __attribute__((ext_vector_type(4))) float f32x4;
typedef __attribute__((ext_vector_type(8))) unsigned short ushort8;
typedef __attribute__((ext_vector_type(2))) unsigned long long u64x2;

#define BM 256
#define BN 256
#define BK 64
#define THREADS 512
#define OPBYTES 32768   // one operand per buf: 256 rows x 128 B
#define BUFBYTES 65536  // A + B
#define LDS_TOTAL 131072

// ---------------- fused quantize: q = rint(v*100)/100, cast to bf16 ----------------
__global__ __launch_bounds__(256) void quant2_bf16_kernel(
    const float* __restrict__ x, const float* __restrict__ w,
    bf16_t* __restrict__ q, long axn8, long totn8) {
  long idx = (long)blockIdx.x * blockDim.x + threadIdx.x;
  long stride = (long)gridDim.x * blockDim.x;
  for (long i = idx; i < totn8; i += stride) {
    const float* src = (i < axn8) ? (x + i * 8) : (w + (i - axn8) * 8);
    const float4* p = reinterpret_cast<const float4*>(src);
    float4 v0 = p[0];
    float4 v1 = p[1];
    float vv[8] = {v0.x, v0.y, v0.z, v0.w, v1.x, v1.y, v1.z, v1.w};
    ushort8 r;
#pragma unroll
    for (int j = 0; j < 8; ++j) {
      float qq = rintf(vv[j] * 100.0f) / 100.0f;  // half-to-even, matches jnp.round
      __hip_bfloat16 h = __float2bfloat16(qq);
      r[j] = __builtin_bit_cast(unsigned short, h);
    }
    u64x2 u = __builtin_bit_cast(u64x2, r);
    unsigned long long* dst = reinterpret_cast<unsigned long long*>(q + i * 8);
    __hip_atomic_store(dst + 0, u[0], __ATOMIC_RELAXED, __HIP_MEMORY_SCOPE_AGENT);
    __hip_atomic_store(dst + 1, u[1], __ATOMIC_RELAXED, __HIP_MEMORY_SCOPE_AGENT);
  }
}

// ---------------- fallback ----------------
__global__ void naive_kernel(const float* __restrict__ x, const float* __restrict__ W,
                             const float* __restrict__ b, float* __restrict__ out,
                             int M, int N, int K) {
  int o = blockIdx.x * blockDim.x + threadIdx.x;
  int m = blockIdx.y;
  if (o >= N || m >= M) return;
  float s = 0.f;
  for (int k = 0; k < K; ++k) {
    float qx = rintf(x[(size_t)m * K + k] * 100.f) / 100.f;
    float qw = rintf(W[(size_t)o * K + k] * 100.f) / 100.f;
    s += qx * qw;
  }
  float v = s + b[o];
  __hip_atomic_store(out + (size_t)m * N + o, v, __ATOMIC_RELAXED,
                     __HIP_MEMORY_SCOPE_AGENT);
}

__device__ __forceinline__ void gload_lds16(const bf16_t* g, const char* l) {
  __builtin_amdgcn_global_load_lds(
      (const __attribute__((address_space(1))) unsigned int*)g,
      (__attribute__((address_space(3))) unsigned int*)l, 16, 0, 0);
}

#define BARRIER()                               \
  do {                                          \
    asm volatile("" ::: "memory");              \
    __builtin_amdgcn_s_barrier();               \
    asm volatile("" ::: "memory");              \
  } while (0)
#define VM8() asm volatile("s_waitcnt vmcnt(8)" ::: "memory")
#define VM0() asm volatile("s_waitcnt vmcnt(0)" ::: "memory")

// ---------------- bf16 GEMM, B^T input: C[m][n] = sum_k A[m][k]*B[n][k] + bias[n]
// ROUND 11 = r8 + TAIL-READS (software-pipelined ds_reads, one phase ahead).
// Diagnosis r6-r10: each phase read-then-consumed in place, so every phase's
// first MFMA waited for the block-wide LDS read burst (8 waves x 12 b128) ->
// LDS pipe and matrix pipe ran in series (9190 cyc/iter = sum, not max).
// Fix (m201's "4 or 8 reads/phase" pattern): issue next phase's reads AFTER
// this phase's MFMA; they drain under the barrier + next phase's start. The
// pre-read time-shares the same registers (WAR handled by wave scoreboard;
// launch_bounds(512,2) caps unified regs at 256 so no renaming blowup).
//
// Read schedule (buf0 half; buf1 mirrors):
//   ph1-top:  blo + A-lo (12)   [cannot pre-read across buf-switch: other
//                                waves' VM8 for this buffer only completes at
//                                the ph8/ph4 barrier -> race. Burst stays.]
//   ph1-tail: bhi (4)           -> consumed ph2
//   ph2-tail: A-hi into aq (8)  -> consumed ph3/ph4 (WAR on aq after MMA(0,1))
//   ph3, ph4: no reads.
// LDS region safety (unchanged from r8): B region's reads all DELIVERED by
// ph2's MFMA lgkm-wait -> stage B @ph3-top (barrier between) OK; A region
// delivered by ph3's MFMA wait -> stage A @ph4-top OK. Register consumption
// at ph4 (aq) is irrelevant to LDS WAR.
// Stage/vmcnt ledger: IDENTICAL to r8 (stages ph3/ph4/ph7/ph8; VM8 at ph4
// retires carried b1(t1), at ph8 retires b0(t2); prologue 16 loads + VM8;
// last iteration peeled with read-at-top + VM0 at ph4).
// LDS swizzle: 128B rows, stored slot = slot ^ (row&7) (0 conflicts measured
// r2-r10). global_load_lds dest linear; swizzle on the global SOURCE (rule #21).
__global__ __launch_bounds__(THREADS, 2) void gemm_bt_bf16(
    const bf16_t* __restrict__ A,   // [M][K]
    const bf16_t* __restrict__ B,   // [N][K]
    const float* __restrict__ bias, // [N]
    float* __restrict__ C,          // [M][N]
    int M, int N, int K) {
  extern __shared__ char lds[];

  const int tid = threadIdx.x;
  const int lane = tid & 63;
  const int wave = tid >> 6;  // 0..7
  const int wm = wave >> 2;   // 0..1 -> output rows wm*128..+128
  const int wn = wave & 3;    // 0..3 -> output cols wn*64..+64
  const int lr = lane & 15;
  const int lg = lane >> 4;

  // XCD-aware bijective swizzle (nwg % 8 == 0 guaranteed by tiled_ok)
  int nbn = N / BN;
  int nwg = gridDim.x;
  int bid = blockIdx.x;
  int swz = bid;
  if ((nwg & 7) == 0) {
    int cpx = nwg >> 3;
    swz = (bid & 7) * cpx + (bid >> 3);
  }
  const int brow = (swz / nbn) * BM;
  const int bcol = (swz % nbn) * BN;

  // ds_read byte offsets within an operand region (kk=0; kk=1 is ^64)
  int aoffs[8], boffs[4];
#pragma unroll
  for (int m = 0; m < 8; ++m) {
    int r = wm * 128 + m * 16 + lr;
    aoffs[m] = r * 128 + (((lg) ^ (r & 7)) << 4);
  }
#pragma unroll
  for (int n = 0; n < 4; ++n) {
    int r = wn * 64 + n * 16 + lr;
    boffs[n] = r * 128 + (((lg) ^ (r & 7)) << 4);
  }

  f32x4 acc[8][4];
#pragma unroll
  for (int m = 0; m < 8; ++m)
#pragma unroll
    for (int n = 0; n < 4; ++n) acc[m][n] = (f32x4){0.f, 0.f, 0.f, 0.f};

  const int nt = K / BK;

  auto STAGE_A = [&](int h, int kt, int q) {
#pragma unroll
    for (int i = 0; i < 2; ++i) {
      int row = h * 128 + i * 64 + (tid >> 3);
      int L = q * BUFBYTES + row * 128 + ((tid & 7) << 4);
      int slot = (tid & 7) ^ (row & 7);
      gload_lds16(A + (size_t)(brow + row) * K + (size_t)kt * 64 + slot * 8,
                  lds + L);
    }
  };
  auto STAGE_B = [&](int h, int kt, int q) {
#pragma unroll
    for (int i = 0; i < 2; ++i) {
      int row = h * 128 + i * 64 + (tid >> 3);
      int L = q * BUFBYTES + OPBYTES + row * 128 + ((tid & 7) << 4);
      int slot = (tid & 7) ^ (row & 7);
      gload_lds16(B + (size_t)(bcol + row) * K + (size_t)kt * 64 + slot * 8,
                  lds + L);
    }
  };

  bf16x8 aq[8], blo[4], bhi[4];  // A quadrant [mm][kk]; B quadrants [nn][kk]
  auto READ_A = [&](int q, int mh) {
#pragma unroll
    for (int mm = 0; mm < 4; ++mm) {
      int off = q * BUFBYTES + aoffs[mh * 4 + mm];
      aq[mm * 2 + 0] = *reinterpret_cast<const bf16x8*>(lds + off);
      aq[mm * 2 + 1] = *reinterpret_cast<const bf16x8*>(lds + (off ^ 64));
    }
  };
  auto READ_B = [&](int q, int nh, bf16x8* dst) {
#pragma unroll
    for (int nn = 0; nn < 2; ++nn) {
      int off = q * BUFBYTES + OPBYTES + boffs[nh * 2 + nn];
      dst[nn * 2 + 0] = *reinterpret_cast<const bf16x8*>(lds + off);
      dst[nn * 2 + 1] = *reinterpret_cast<const bf16x8*>(lds + (off ^ 64));
    }
  };
  auto MMA = [&](int mh, int nh, const bf16x8* bb) {
    __builtin_amdgcn_s_setprio(1);
#pragma unroll
    for (int mm = 0; mm < 4; ++mm)
#pragma unroll
      for (int nn = 0; nn < 2; ++nn)
#pragma unroll
        for (int kk = 0; kk < 2; ++kk)
          acc[mh * 4 + mm][nh * 2 + nn] = __builtin_amdgcn_mfma_f32_16x16x32_bf16(
              aq[mm * 2 + kk], bb[nn * 2 + kk], acc[mh * 4 + mm][nh * 2 + nn],
              0, 0, 0);
    __builtin_amdgcn_s_setprio(0);
  };

  // Prologue: both tiles fully staged; b0's 8 retired, b1's 8 carried in flight.
  STAGE_B(0, 0, 0); STAGE_B(1, 0, 0); STAGE_A(0, 0, 0); STAGE_A(1, 0, 0);
  STAGE_B(0, 1, 1); STAGE_B(1, 1, 1); STAGE_A(0, 1, 1); STAGE_A(1, 1, 1);
  VM8();
  BARRIER();

  const int np = nt >> 1;
  for (int p = 0; p < np - 1; ++p) {
    const int t2 = 2 * p + 2, t3 = 2 * p + 3;
    // ph1: buf0 (m-lo,n-lo). Top-burst (unavoidable at buf switch), then
    // tail pre-read of bhi for ph2.
    READ_B(0, 0, blo); READ_A(0, 0);
    MMA(0, 0, blo);
    READ_B(0, 1, bhi);
    BARRIER();
    // ph2: (m-lo,n-hi) — operands pre-read. Tail pre-read A-hi for ph3/ph4
    // (WAR on aq: issued after MMA(0,1) consumed A-lo).
    MMA(0, 1, bhi);
    READ_A(0, 1);
    BARRIER();
    // ph3: (m-hi,n-hi) — no reads; stage b0.B(t2) (B reads delivered by ph2)
    STAGE_B(0, t2, 0); STAGE_B(1, t2, 0);
    MMA(1, 1, bhi);
    BARRIER();
    // ph4: (m-hi,n-lo) — no reads; stage b0.A(t2); retire carried b1(t1)
    STAGE_A(0, t2, 0); STAGE_A(1, t2, 0);
    MMA(1, 0, blo);
    VM8();
    BARRIER();
    // ph5: buf1 — mirror of ph1
    READ_B(1, 0, blo); READ_A(1, 0);
    MMA(0, 0, blo);
    READ_B(1, 1, bhi);
    BARRIER();
    // ph6 — mirror of ph2
    MMA(0, 1, bhi);
    READ_A(1, 1);
    BARRIER();
    // ph7 — stage b1.B(t3)
    STAGE_B(0, t3, 1); STAGE_B(1, t3, 1);
    MMA(1, 1, bhi);
    BARRIER();
    // ph8 — stage b1.A(t3); retire b0(t2)
    STAGE_A(0, t3, 1); STAGE_A(1, t3, 1);
    MMA(1, 0, blo);
    VM8();
    BARRIER();
  }

  // Peeled final iteration (r8-proven): read-at-top, no stages, VM0 at ph4.
  {
    READ_B(0, 0, blo); READ_A(0, 0);
    MMA(0, 0, blo);
    BARRIER();
    READ_B(0, 1, bhi);
    MMA(0, 1, bhi);
    BARRIER();
    READ_A(0, 1);
    MMA(1, 1, bhi);
    BARRIER();
    MMA(1, 0, blo);
    VM0();
    BARRIER();
    READ_B(1, 0, blo); READ_A(1, 0);
    MMA(0, 0, blo);
    BARRIER();
    READ_B(1, 1, bhi);
    MMA(0, 1, bhi);
    BARRIER();
    READ_A(1, 1);
    MMA(1, 1, bhi);
    BARRIER();
    MMA(1, 0, blo);
  }

  // Epilogue: C/D layout col=lane&15, row=(lane>>4)*4+reg  [m89/m91]
  // Agent-scope stores (replay-safe visibility past per-XCD L2).
  const int cn = lane & 15;
  const int r4 = (lane >> 4) << 2;
#pragma unroll
  for (int n = 0; n < 4; ++n) {
    const int gcol = bcol + wn * 64 + n * 16 + cn;
    const float bv = bias[gcol];
#pragma unroll
    for (int m = 0; m < 8; ++m) {
      const int grow = brow + wm * 128 + m * 16 + r4;
      float* outp = C + (size_t)grow * N + gcol;
#pragma unroll
      for (int j = 0; j < 4; ++j) {
        float v = acc[m][n][j] + bv;
        __hip_atomic_store(outp + (size_t)j * N, v, __ATOMIC_RELAXED,
                           __HIP_MEMORY_SCOPE_AGENT);
      }
    }
  }
}

extern "C" void kernel_launch(void* const* d_in, const int* in_sizes, int n_in,
                              void* d_out, int out_size, void* d_ws, size_t ws_size,
                              hipStream_t stream) {
  const float* x = (const float*)d_in[0];
  const float* W = (const float*)d_in[1];
  const float* b = (const float*)d_in[2];
  float* out = (float*)d_out;

  const int N = in_sizes[2];       // D_OUT
  const int K = in_sizes[1] / N;   // D_IN
  const int M = in_sizes[0] / K;   // B rows

  const size_t needA = (size_t)M * K * sizeof(bf16_t);
  const size_t needB = (size_t)N * K * sizeof(bf16_t);
  const bool tiled_ok = (M % BM == 0) && (N % BN == 0) && (K % (2 * BK) == 0) &&
                        (K / BK >= 2) && (ws_size >= needA + needB);
  if (!tiled_ok) {
    dim3 g((unsigned)((N + 255) / 256), (unsigned)M);
    naive_kernel<<<g, 256, 0, stream>>>(x, W, b, out, M, N, K);
    return;
  }

  bf16_t* qA = (bf16_t*)d_ws;
  bf16_t* qB = qA + (size_t)M * K;
  const long axn8 = (long)M * K / 8;
  const long totn8 = axn8 + (long)N * K / 8;
  quant2_bf16_kernel<<<2048, 256, 0, stream>>>(x, W, qA, axn8, totn8);

  (void)hipFuncSetAttribute((const void*)gemm_bt_bf16,
                            hipFuncAttributeMaxDynamicSharedMemorySize, LDS_TOTAL);

  const int nwg = (M / BM) * (N / BN);
  gemm_bt_bf16<<<nwg, THREADS, LDS_TOTAL, stream>>>(qA, qB, b, out, M, N, K);
}